// Round 5
// baseline (476.256 us; speedup 1.0000x reference)
//
#include <hip/hip_runtime.h>

// ---------------------------------------------------------------------------
// QuantizedAttention: x[B,S,D] -> QKV proj (int8-quant wts) -> RMSNorm -> RoPE
//   -> causal GQA attention -> O proj.  B=2 S=2048 D=2048 H=16 KVH=8 HD=128.
// R5: RMSNorm+RoPE+V-transpose fused into the QKV GEMM epilogue (the 128-col
// N-tile is exactly one head; RoPE pairs t<->t+64 inside the tile and
// cos[t]==cos[t+64]); output conversion fused into the O-proj GEMM epilogue.
// Deletes rmsrope / vtrans / out_conv and the 67MB fp32 qkvf round-trip.
// attn unchanged from R4 (q-split waves, no-max softmax, S^T layout,
// global_load_lds + XOR swizzle + double buffer).
// ---------------------------------------------------------------------------

typedef __attribute__((ext_vector_type(4))) float floatx4;
typedef __attribute__((ext_vector_type(8))) short short8v;
typedef __attribute__((ext_vector_type(4))) short short4v;
typedef __attribute__((ext_vector_type(8))) unsigned short ushort8v;
typedef __attribute__((ext_vector_type(4))) unsigned short ushort4v;

#define DEVINL __device__ __forceinline__

constexpr int cB = 2, cS = 2048, cD = 2048, cH = 16, cKVH = 8, cHD = 128;
constexpr int cM = cB * cS;
constexpr int cNqkv = (cH + 2 * cKVH) * cHD;
constexpr float cEPS = 1e-6f;
constexpr float cSCALE = 0.08838834764831845f;   // 1/sqrt(HD)

DEVINL unsigned short f2bf(float f) {
  unsigned u = __float_as_uint(f);
  unsigned r = ((u >> 16) & 1u) + 0x7FFFu;
  return (unsigned short)((u + r) >> 16);
}
DEVINL float bf2f(unsigned short h) { return __uint_as_float(((unsigned)h) << 16); }

DEVINL floatx4 mfma_bf16(short8v a, short8v b, floatx4 c) {
  return __builtin_amdgcn_mfma_f32_16x16x32_bf16(a, b, c, 0, 0, 0);
}

DEVINL floatx4 mfma_pv(short4v a, short4v b, floatx4 c) {
#if __has_builtin(__builtin_amdgcn_mfma_f32_16x16x16bf16_1k)
  return __builtin_amdgcn_mfma_f32_16x16x16bf16_1k(a, b, c, 0, 0, 0);
#else
  short8v a8 = {a[0], a[1], a[2], a[3], (short)0, (short)0, (short)0, (short)0};
  short8v b8 = {b[0], b[1], b[2], b[3], (short)0, (short)0, (short)0, (short)0};
  return __builtin_amdgcn_mfma_f32_16x16x32_bf16(a8, b8, c, 0, 0, 0);
#endif
}

DEVINL void gl_lds16(const void* g, void* l) {
  __builtin_amdgcn_global_load_lds(
      (const __attribute__((address_space(1))) void*)g,
      (__attribute__((address_space(3))) void*)l, 16, 0, 0);
}

// --------------------------- dtype detection -------------------------------
__global__ void detect_dtype(const unsigned* __restrict__ x, int* __restrict__ flag) {
  __shared__ int cnt;
  if (threadIdx.x == 0) cnt = 0;
  __syncthreads();
  int c = 0;
  for (int i = threadIdx.x; i < 4096; i += 256) {
    unsigned e = (x[i] >> 7) & 0xFFu;
    c += (e >= 100u && e <= 142u) ? 1 : 0;
  }
  atomicAdd(&cnt, c);
  __syncthreads();
  if (threadIdx.x == 0) *flag = (cnt > 2457) ? 1 : 0;  // 1 = host is bf16
}

// --------------------------- conversions -----------------------------------
__global__ void conv_x(const void* __restrict__ src, unsigned short* __restrict__ dst,
                       int n, const int* __restrict__ flag) {
  int i = (blockIdx.x * 256 + threadIdx.x) * 8;
  if (i >= n) return;
  if (*flag) {
    *(ushort8v*)(dst + i) = *(const ushort8v*)((const unsigned short*)src + i);
  } else {
    const float* s = (const float*)src;
    ushort8v o;
#pragma unroll
    for (int j = 0; j < 8; j++) o[j] = f2bf(s[i + j]);
    *(ushort8v*)(dst + i) = o;
  }
}

__global__ void conv_f32(const void* __restrict__ src, float* __restrict__ dst,
                         int n, const int* __restrict__ flag) {
  int i = blockIdx.x * 256 + threadIdx.x;
  if (i >= n) return;
  dst[i] = (*flag) ? bf2f(((const unsigned short*)src)[i]) : ((const float*)src)[i];
}

__global__ void conv_w(const int* __restrict__ w, unsigned short* __restrict__ dst, int n) {
  int i = (blockIdx.x * 256 + threadIdx.x) * 4;
  if (i >= n) return;
  int4 v = *(const int4*)(w + i);
  ushort4v o;
  o[0] = f2bf((float)v.x); o[1] = f2bf((float)v.y);
  o[2] = f2bf((float)v.z); o[3] = f2bf((float)v.w);
  *(ushort4v*)(dst + i) = o;
}

// Packed RoPE table: tab[s*64+t] = {cos[s,t], sin[s,t]} for t<64 (halves equal).
__global__ void rope_pack(const void* __restrict__ cosc, const void* __restrict__ sinc,
                          float2* __restrict__ tab, const int* __restrict__ flag) {
  int i = blockIdx.x * 256 + threadIdx.x;   // 2048*64
  if (i >= cS * 64) return;
  int s = i >> 6, t = i & 63;
  int f = *flag;
  float c = f ? bf2f(((const unsigned short*)cosc)[s * cHD + t])
              : ((const float*)cosc)[s * cHD + t];
  float sn = f ? bf2f(((const unsigned short*)sinc)[s * cHD + t])
               : ((const float*)sinc)[s * cHD + t];
  tab[i] = make_float2(c, sn);
}

// ------------------- fused QKV GEMM + RMSNorm + RoPE + V^T -----------------
// C = (x @ Wqkv^T)*scale, 128x128x64 tiles. N-tile == one head:
//   tiles 0..15 -> Q head, 16..23 -> K head (RMSNorm+RoPE, bf16 -> Qb/Kb),
//   tiles 24..31 -> V head (bf16 transposed -> Vt[B,KVH,HD,S]).
__global__ __launch_bounds__(256) void gemm_qkv(
    const unsigned short* __restrict__ A, const unsigned short* __restrict__ Bw,
    const float* __restrict__ colscale, const float2* __restrict__ ropetab,
    const float* __restrict__ nw, unsigned short* __restrict__ Qb,
    unsigned short* __restrict__ Kb, unsigned short* __restrict__ Vt) {
  __shared__ float4 smem4[2192];            // 35072 B
  char* smem = (char*)smem4;
  unsigned short* As = (unsigned short*)smem;         // 16 KiB
  unsigned short* Bs = As + 8192;                     // 16 KiB
  const int tid = threadIdx.x;
  const int lane = tid & 63, wave = tid >> 6;
  const int q = lane >> 4, l16 = lane & 15;
  const int m0 = blockIdx.y * 128, n0 = blockIdx.x * 128;
  const int wm = (wave & 1) * 64, wn = (wave >> 1) * 64;

  floatx4 acc[4][4] = {};

  int goff[4];
#pragma unroll
  for (int i = 0; i < 4; i++) {
    int s = (wave * 4 + i) * 64 + lane;
    int r = s >> 3, u = (s & 7) ^ (r & 7);
    goff[i] = r * cD + u * 8;
  }
  const unsigned short* Ag = A + (size_t)m0 * cD;
  const unsigned short* Bg = Bw + (size_t)n0 * cD;

  for (int k0 = 0; k0 < cD; k0 += 64) {
    __syncthreads();
#pragma unroll
    for (int i = 0; i < 4; i++)
      gl_lds16(Ag + k0 + goff[i], (char*)As + (wave * 4 + i) * 1024);
#pragma unroll
    for (int i = 0; i < 4; i++)
      gl_lds16(Bg + k0 + goff[i], (char*)Bs + (wave * 4 + i) * 1024);
    __syncthreads();
#pragma unroll
    for (int kk = 0; kk < 2; kk++) {
      short8v af[4], bf[4];
#pragma unroll
      for (int mt = 0; mt < 4; mt++) {
        int row = wm + mt * 16 + l16;
        af[mt] = *(const short8v*)(As + row * 64 + (((kk * 4 + q) ^ (l16 & 7)) * 8));
      }
#pragma unroll
      for (int nt = 0; nt < 4; nt++) {
        int row = wn + nt * 16 + l16;
        bf[nt] = *(const short8v*)(Bs + row * 64 + (((kk * 4 + q) ^ (l16 & 7)) * 8));
      }
#pragma unroll
      for (int mt = 0; mt < 4; mt++)
#pragma unroll
        for (int nt = 0; nt < 4; nt++)
          acc[mt][nt] = mfma_bf16(af[mt], bf[nt], acc[mt][nt]);
    }
  }

  // ---- epilogue ----
  float sc[4];
#pragma unroll
  for (int nt = 0; nt < 4; nt++) sc[nt] = colscale[n0 + wn + nt * 16 + l16];
#pragma unroll
  for (int mt = 0; mt < 4; mt++)
#pragma unroll
    for (int nt = 0; nt < 4; nt++)
#pragma unroll
      for (int rg = 0; rg < 4; rg++) acc[mt][nt][rg] *= sc[nt];

  const int tile_n = blockIdx.x;
  const int bi = m0 >> 11, sbase = m0 & (cS - 1);
  __syncthreads();                          // main-loop LDS reads complete

  if (tile_n >= 24) {
    // ---------------- V: transpose through LDS, store Vt[.,d,s] ----------
    unsigned short* T = (unsigned short*)smem;   // [128 d][136 s]
#pragma unroll
    for (int mt = 0; mt < 4; mt++)
#pragma unroll
      for (int nt = 0; nt < 4; nt++) {
        short4v pk;
#pragma unroll
        for (int rg = 0; rg < 4; rg++) pk[rg] = (short)f2bf(acc[mt][nt][rg]);
        *(short4v*)(T + (wn + nt * 16 + l16) * 136 + (wm + mt * 16 + q * 4)) = pk;
      }
    __syncthreads();
    const int d = tid >> 1, sh = (tid & 1) * 64;
    unsigned short* dst = Vt + ((size_t)(bi * cKVH + (tile_n - 24)) * cHD + d) * cS
                          + sbase + sh;
#pragma unroll
    for (int j = 0; j < 8; j++)
      *(ushort8v*)(dst + j * 8) = *(const ushort8v*)(T + d * 136 + sh + j * 8);
  } else {
    // ---------------- Q/K: RMSNorm + RoPE --------------------------------
    unsigned short* W = (unsigned short*)smem;   // 4 waves x 4096 ushorts
    float* ssq  = (float*)(smem + 32768);        // [2][128]
    float* invs = (float*)(smem + 33792);        // [128]

    // per-row sumsq over this wave's 64 cols
    float sl[4][4];
#pragma unroll
    for (int mt = 0; mt < 4; mt++)
#pragma unroll
      for (int rg = 0; rg < 4; rg++) {
        float s = 0.f;
#pragma unroll
        for (int nt = 0; nt < 4; nt++) s += acc[mt][nt][rg] * acc[mt][nt][rg];
        s += __shfl_xor(s, 1); s += __shfl_xor(s, 2);
        s += __shfl_xor(s, 4); s += __shfl_xor(s, 8);
        sl[mt][rg] = s;
      }
    // exchange buffer (bf16, raw fragment order: rg contiguous)
    unsigned short* Wo = W + wave * 4096;
#pragma unroll
    for (int mt = 0; mt < 4; mt++)
#pragma unroll
      for (int nt = 0; nt < 4; nt++) {
        short4v pk;
#pragma unroll
        for (int rg = 0; rg < 4; rg++) pk[rg] = (short)f2bf(acc[mt][nt][rg]);
        *(short4v*)(Wo + (mt * 4 + nt) * 256 + lane * 4) = pk;
      }
    if (l16 == 0) {
#pragma unroll
      for (int mt = 0; mt < 4; mt++)
#pragma unroll
        for (int rg = 0; rg < 4; rg++)
          ssq[((wave >> 1) & 1) * 128 + wm + mt * 16 + q * 4 + rg] = sl[mt][rg];
    }
    __syncthreads();
    if (tid < 128)
      invs[tid] = rsqrtf((ssq[tid] + ssq[128 + tid]) * (1.0f / cHD) + cEPS);
    __syncthreads();

    const unsigned short* Wp = W + (wave ^ 2) * 4096;  // partner: other col half
    const int wn1 = wave >> 1;               // 0: cols t, 1: cols t+64
    const float* nwb = nw + (tile_n < 16 ? 0 : cHD);
    float wown[4], wpar[4];
#pragma unroll
    for (int nt = 0; nt < 4; nt++) {
      wown[nt] = nwb[wn1 * 64 + nt * 16 + l16];
      wpar[nt] = nwb[(wn1 ^ 1) * 64 + nt * 16 + l16];
    }
    unsigned short* dstb = (tile_n < 16)
        ? Qb + ((size_t)(bi * cH + tile_n) * cS) * cHD
        : Kb + ((size_t)(bi * cKVH + (tile_n - 16)) * cS) * cHD;
#pragma unroll
    for (int mt = 0; mt < 4; mt++) {
      float iv[4];
#pragma unroll
      for (int rg = 0; rg < 4; rg++) iv[rg] = invs[wm + mt * 16 + q * 4 + rg];
#pragma unroll
      for (int nt = 0; nt < 4; nt++) {
        short4v pk = *(const short4v*)(Wp + (mt * 4 + nt) * 256 + lane * 4);
#pragma unroll
        for (int rg = 0; rg < 4; rg++) {
          int srow = sbase + wm + mt * 16 + q * 4 + rg;
          float2 cs = ropetab[srow * 64 + nt * 16 + l16];
          float nown = acc[mt][nt][rg] * iv[rg] * wown[nt];
          float npar = bf2f((unsigned short)pk[rg]) * iv[rg] * wpar[nt];
          float o = wn1 == 0 ? nown * cs.x - npar * cs.y
                             : nown * cs.x + npar * cs.y;
          dstb[(size_t)srow * cHD + wn1 * 64 + nt * 16 + l16] = f2bf(o);
        }
      }
    }
  }
}

// ------------------- O-proj GEMM with fused flag-output --------------------
__global__ __launch_bounds__(256) void gemm_out(
    const unsigned short* __restrict__ A, const unsigned short* __restrict__ Bw,
    const float* __restrict__ colscale, void* __restrict__ Cout,
    const int* __restrict__ flag, int M, int N, int K) {
  __shared__ unsigned short As[128 * 64];
  __shared__ unsigned short Bs[128 * 64];
  const int tid = threadIdx.x;
  const int lane = tid & 63, wave = tid >> 6;
  const int q = lane >> 4, l16 = lane & 15;
  const int m0 = blockIdx.y * 128, n0 = blockIdx.x * 128;
  const int wm = (wave & 1) * 64, wn = (wave >> 1) * 64;

  floatx4 acc[4][4] = {};

  int goff[4];
#pragma unroll
  for (int i = 0; i < 4; i++) {
    int s = (wave * 4 + i) * 64 + lane;
    int r = s >> 3, u = (s & 7) ^ (r & 7);
    goff[i] = r * K + u * 8;
  }
  const unsigned short* Ag = A + (size_t)m0 * K;
  const unsigned short* Bg = Bw + (size_t)n0 * K;

  for (int k0 = 0; k0 < K; k0 += 64) {
    __syncthreads();
#pragma unroll
    for (int i = 0; i < 4; i++)
      gl_lds16(Ag + k0 + goff[i], (char*)As + (wave * 4 + i) * 1024);
#pragma unroll
    for (int i = 0; i < 4; i++)
      gl_lds16(Bg + k0 + goff[i], (char*)Bs + (wave * 4 + i) * 1024);
    __syncthreads();
#pragma unroll
    for (int kk = 0; kk < 2; kk++) {
      short8v af[4], bf[4];
#pragma unroll
      for (int mt = 0; mt < 4; mt++) {
        int row = wm + mt * 16 + l16;
        af[mt] = *(const short8v*)(As + row * 64 + (((kk * 4 + q) ^ (l16 & 7)) * 8));
      }
#pragma unroll
      for (int nt = 0; nt < 4; nt++) {
        int row = wn + nt * 16 + l16;
        bf[nt] = *(const short8v*)(Bs + row * 64 + (((kk * 4 + q) ^ (l16 & 7)) * 8));
      }
#pragma unroll
      for (int mt = 0; mt < 4; mt++)
#pragma unroll
        for (int nt = 0; nt < 4; nt++)
          acc[mt][nt] = mfma_bf16(af[mt], bf[nt], acc[mt][nt]);
    }
  }
  const int f = *flag;
#pragma unroll
  for (int mt = 0; mt < 4; mt++) {
    int r0 = m0 + wm + mt * 16 + q * 4;
#pragma unroll
    for (int nt = 0; nt < 4; nt++) {
      int cn = n0 + wn + nt * 16 + l16;
      float sc = colscale[cn];
#pragma unroll
      for (int rg = 0; rg < 4; rg++) {
        float v = acc[mt][nt][rg] * sc;
        if (f) ((unsigned short*)Cout)[(size_t)(r0 + rg) * N + cn] = f2bf(v);
        else   ((float*)Cout)[(size_t)(r0 + rg) * N + cn] = v;
      }
    }
  }
}

// --------------------------- flash attention (v4, unchanged) ---------------
__global__ __launch_bounds__(256, 2) void attn(
    const unsigned short* __restrict__ Qb, const unsigned short* __restrict__ Kb,
    const unsigned short* __restrict__ Vt, unsigned short* __restrict__ AO) {
  __shared__ unsigned short SM[32768];
  const int tid = threadIdx.x;
  const int lane = tid & 63, wv = tid >> 6;
  const int q = lane >> 4, l16 = lane & 15;
  const int bi = blockIdx.z, h = blockIdx.y;
  const int kh = h >> 1;
  const int qt = (int)gridDim.x - 1 - (int)blockIdx.x;
  const int q0 = qt * 64;
  const int q0w = q0 + wv * 16;

  const unsigned short* Qbase = Qb + ((size_t)(bi * cH + h) * cS + q0w) * cHD;
  const unsigned short* Kbase = Kb + ((size_t)(bi * cKVH + kh) * cS) * cHD;
  const unsigned short* Vbase = Vt + ((size_t)(bi * cKVH + kh) * cHD) * cS;

  short8v qa[4];
#pragma unroll
  for (int c = 0; c < 4; c++)
    qa[c] = *(const short8v*)(Qbase + (size_t)l16 * cHD + c * 32 + q * 8);

  floatx4 oacc[8] = {};
  float lp = 0.f;

  int koff[4], voff[4];
#pragma unroll
  for (int i = 0; i < 4; i++) {
    int s = (wv * 4 + i) * 64 + lane;
    int r = s >> 4, u = (s & 15) ^ (r & 15);
    koff[i] = r * cHD + u * 8;
    int d = s >> 3, uv = (s & 7) ^ (d & 7);
    voff[i] = d * cS + uv * 8;
  }

  auto stage = [&](int win) {
    const int buf = (win & 1) * 16384;
    const int kv0 = win * 64;
    unsigned short* Kdst = SM + buf + (wv * 4) * 512;
    unsigned short* Vdst = SM + buf + 8192 + (wv * 4) * 512;
#pragma unroll
    for (int i = 0; i < 4; i++)
      gl_lds16(Kbase + (size_t)kv0 * cHD + koff[i], Kdst + i * 512);
#pragma unroll
    for (int i = 0; i < 4; i++)
      gl_lds16(Vbase + (size_t)kv0 + voff[i], Vdst + i * 512);
  };

  stage(0);
  for (int win = 0; win <= qt; win++) {
    __syncthreads();
    if (win < qt) stage(win + 1);
    const unsigned short* Ks = SM + (win & 1) * 16384;
    const unsigned short* Vs = Ks + 8192;

    floatx4 sres[4] = {};
#pragma unroll
    for (int c = 0; c < 4; c++) {
      short8v kf[4];
#pragma unroll
      for (int ntk = 0; ntk < 4; ntk++)
        kf[ntk] = *(const short8v*)(Ks + (ntk * 16 + l16) * 128 + (((c * 4 + q) ^ l16) * 8));
#pragma unroll
      for (int ntk = 0; ntk < 4; ntk++)
        sres[ntk] = mfma_bf16(kf[ntk], qa[c], sres[ntk]);
    }

    const bool lastwin = (win == qt);
    short4v pa[4];
#pragma unroll
    for (int ntk = 0; ntk < 4; ntk++) {
#pragma unroll
      for (int rg = 0; rg < 4; rg++) {
        float e = __expf(sres[ntk][rg] * cSCALE);
        if (lastwin && (ntk * 16 + q * 4 + rg > wv * 16 + l16)) e = 0.f;
        lp += e;
        pa[ntk][rg] = (short)f2bf(e);
      }
    }

#pragma unroll
    for (int ntk = 0; ntk < 4; ntk++) {
#pragma unroll
      for (int db = 0; db < 8; db++) {
        short4v vb = *(const short4v*)(Vs + (db * 16 + l16) * 64 +
                       (((ntk * 2 + (q >> 1)) ^ (l16 & 7)) * 8 + (q & 1) * 4));
        oacc[db] = mfma_pv(pa[ntk], vb, oacc[db]);
      }
    }
  }

  float lf = lp;
  lf += __shfl_xor(lf, 16);
  lf += __shfl_xor(lf, 32);
  float li[4];
#pragma unroll
  for (int rg = 0; rg < 4; rg++) li[rg] = 1.0f / __shfl(lf, q * 4 + rg);

#pragma unroll
  for (int rg = 0; rg < 4; rg++) {
    int row = q0w + q * 4 + rg;
    unsigned short* dst = AO + (size_t)(bi * cS + row) * (cH * cHD) + h * cHD;
#pragma unroll
    for (int db = 0; db < 8; db++)
      dst[db * 16 + l16] = f2bf(oacc[db][rg] * li[rg]);
  }
}

// --------------------------- launch ----------------------------------------
extern "C" void kernel_launch(void* const* d_in, const int* in_sizes, int n_in,
                              void* d_out, int out_size, void* d_ws, size_t ws_size,
                              hipStream_t stream) {
  (void)in_sizes; (void)n_in; (void)out_size; (void)ws_size;
  char* ws = (char*)d_ws;
  size_t off = 0;
  auto alloc = [&](size_t bytes) -> char* {
    char* p = ws + off;
    off += (bytes + 255) & ~((size_t)255);
    return p;
  };
  int* flag            = (int*)alloc(256);
  float2* ropetab      = (float2*)alloc((size_t)cS * 64 * 8);
  float* nw            = (float*)alloc(256 * 4);
  float* scat          = (float*)alloc(4096 * 4);
  float* so            = (float*)alloc(2048 * 4);
  unsigned short* xb   = (unsigned short*)alloc((size_t)cM * cD * 2);
  unsigned short* wcat = (unsigned short*)alloc((size_t)cNqkv * cD * 2);
  unsigned short* wob  = (unsigned short*)alloc((size_t)cD * cH * cHD * 2);
  unsigned short* Qb   = (unsigned short*)alloc((size_t)cB * cH * cS * cHD * 2);
  unsigned short* Kb   = (unsigned short*)alloc((size_t)cB * cKVH * cS * cHD * 2);
  unsigned short* Vt   = (unsigned short*)alloc((size_t)cB * cKVH * cHD * cS * 2);
  unsigned short* AO   = (unsigned short*)alloc((size_t)cM * cD * 2);

  detect_dtype<<<1, 256, 0, stream>>>((const unsigned*)d_in[0], flag);

  conv_x<<<(cM * cD / 8 + 255) / 256, 256, 0, stream>>>(d_in[0], xb, cM * cD, flag);
  rope_pack<<<(cS * 64 + 255) / 256, 256, 0, stream>>>(d_in[11], d_in[12], ropetab, flag);
  conv_f32<<<1, 256, 0, stream>>>(d_in[9], nw, cHD, flag);
  conv_f32<<<1, 256, 0, stream>>>(d_in[10], nw + cHD, cHD, flag);
  conv_f32<<<8, 256, 0, stream>>>(d_in[2], scat, 2048, flag);
  conv_f32<<<4, 256, 0, stream>>>(d_in[4], scat + 2048, 1024, flag);
  conv_f32<<<4, 256, 0, stream>>>(d_in[6], scat + 3072, 1024, flag);
  conv_f32<<<8, 256, 0, stream>>>(d_in[8], so, 2048, flag);
  conv_w<<<(2048 * 2048 / 4 + 255) / 256, 256, 0, stream>>>((const int*)d_in[1], wcat, 2048 * 2048);
  conv_w<<<(1024 * 2048 / 4 + 255) / 256, 256, 0, stream>>>((const int*)d_in[3], wcat + (size_t)2048 * 2048, 1024 * 2048);
  conv_w<<<(1024 * 2048 / 4 + 255) / 256, 256, 0, stream>>>((const int*)d_in[5], wcat + (size_t)3072 * 2048, 1024 * 2048);
  conv_w<<<(2048 * 2048 / 4 + 255) / 256, 256, 0, stream>>>((const int*)d_in[7], wob, 2048 * 2048);

  gemm_qkv<<<dim3(cNqkv / 128, cM / 128), 256, 0, stream>>>(
      xb, wcat, scat, ropetab, nw, Qb, Kb, Vt);
  attn<<<dim3(cS / 64, cH, cB), 256, 0, stream>>>(Qb, Kb, Vt, AO);
  gemm_out<<<dim3(cD / 128, cM / 128), 256, 0, stream>>>(
      AO, wob, so, d_out, flag, cM, cD, cH * cHD);
}